// Round 5
// baseline (272.197 us; speedup 1.0000x reference)
//
#include <hip/hip_runtime.h>
#include <cstdint>
#include <cstddef>

#define WPITCH 24

// ws layout (float offsets)
#define WS_WBIG 0            // 3072*24 = 73728
#define WS_BMAT 73728        // 640*24  = 15360
#define WS_BBIG 89088        // 24 (+pad)
#define WS_ND   89728        // 8192*23 = 188416
#define WS_REL  278144       // 28672*23 = 659456

// output offsets (floats)
#define OUT_IND 0
#define OUT_LAB 28672
#define OUT_LRP 57344
#define OUT_CRP 98304
#define OUT_MRP 122880
#define OUT_LRN 237568
#define OUT_CRN 339968
#define OUT_MRN 401408

__device__ __constant__ int d_pi[28] = {0,0,0,0,0,0,0,1,1,1,1,1,1,2,2,2,2,2,3,3,3,3,4,4,4,5,5,6};
__device__ __constant__ int d_pj[28] = {1,2,3,4,5,6,7,2,3,4,5,6,7,3,4,5,6,7,4,5,6,7,5,6,7,6,7,7};

__device__ __forceinline__ float wh_at(const float* wlr, const float* wcr, const float* wmr,
                                       int j, int h) {
  return (h < 5) ? wlr[j*5 + h] : (h < 8) ? wcr[j*3 + (h-5)] : wmr[j*14 + (h-8)];
}

__device__ __forceinline__ const float* uniform_ptr(const float* p) {
  uint64_t u = (uint64_t)p;
  uint32_t lo = __builtin_amdgcn_readfirstlane((uint32_t)(u & 0xffffffffu));
  uint32_t hi = __builtin_amdgcn_readfirstlane((uint32_t)(u >> 32));
  return (const float*)(((uint64_t)hi << 32) | lo);
}

// global -> LDS direct (16B per lane); LDS dest = wave-uniform base + lane*16
__device__ __forceinline__ void load_lds16(const float* g, float* l) {
  __builtin_amdgcn_global_load_lds((const __attribute__((address_space(1))) void*)g,
                                   (__attribute__((address_space(3))) void*)l, 16, 0, 0);
}

// ---------------- prep1: Bmat = [T1(128x24); WhE(512x24)] and b_big ----------------
__global__ __launch_bounds__(256) void prep1(
    const float* __restrict__ w_rel, const float* __restrict__ w_ind2,
    const float* __restrict__ w_lr, const float* __restrict__ w_cr, const float* __restrict__ w_mr,
    const float* __restrict__ b_ind1, const float* __restrict__ b_ind2,
    const float* __restrict__ b_rel,
    const float* __restrict__ b_lr, const float* __restrict__ b_cr, const float* __restrict__ b_mr,
    float* __restrict__ bmat, float* __restrict__ bbig) {
  int bid = blockIdx.x, tid = threadIdx.x;
  if (bid < 128) {                         // T1[m][1+h] = sum_j Wrel2[m][j]*Wh[j][h]
    int m = bid;
    __shared__ float swr[512];
    const float* wr2 = w_rel + (size_t)(3072 + m)*512;
    swr[tid]       = wr2[tid];
    swr[tid + 256] = wr2[tid + 256];
    __syncthreads();
    int h = tid >> 3, q = tid & 7;
    if (h < 22) {
      float a = 0.f;
#pragma unroll 8
      for (int jj = 0; jj < 64; ++jj) {
        int j = jj*8 + q;
        a = fmaf(swr[j], wh_at(w_lr, w_cr, w_mr, j, h), a);
      }
      a += __shfl_xor(a, 1); a += __shfl_xor(a, 2); a += __shfl_xor(a, 4);
      if (q == 0) bmat[m*24 + 1 + h] = a;
    }
    if (tid == 248) bmat[m*24 + 0]  = w_ind2[m];
    if (tid == 249) bmat[m*24 + 23] = 0.f;
  } else if (bid == 128) {                 // biases
    __shared__ float sbrel[512];
    for (int j = tid; j < 512; j += 256) {
      float a = b_rel[j];
#pragma unroll 4
      for (int m = 0; m < 128; ++m)
        a = fmaf(b_ind1[m], w_rel[(size_t)(3072 + m)*512 + j], a);
      sbrel[j] = a;
    }
    __syncthreads();
    int h = tid >> 3, q = tid & 7;
    if (h < 22) {
      float bh = (h < 5) ? b_lr[h] : (h < 8) ? b_cr[h-5] : b_mr[h-8];
      float a = 0.f;
#pragma unroll 8
      for (int jj = 0; jj < 64; ++jj) {
        int j = jj*8 + q;
        a = fmaf(sbrel[j], wh_at(w_lr, w_cr, w_mr, j, h), a);
      }
      a += __shfl_xor(a, 1); a += __shfl_xor(a, 2); a += __shfl_xor(a, 4);
      if (q == 0) bbig[1 + h] = a + bh;
    } else if (tid >= 248) {
      int q2 = tid & 7;
      float a = 0.f;
#pragma unroll
      for (int t = 0; t < 16; ++t)
        a = fmaf(b_ind1[q2*16 + t], w_ind2[q2*16 + t], a);
      a += __shfl_xor(a, 1); a += __shfl_xor(a, 2); a += __shfl_xor(a, 4);
      if (tid == 248) bbig[0]  = a + b_ind2[0];
      if (tid == 250) bbig[23] = 0.f;
    }
  } else {                                 // WhE copy: bids 129..176
    int idx = (bid - 129)*256 + tid;
    int j = idx / 24, n = idx % 24;
    float v = (n >= 1 && n <= 22) ? wh_at(w_lr, w_cr, w_mr, j, n - 1) : 0.f;
    bmat[(128 + j)*24 + n] = v;
  }
}

// ---------------- prep2: W_big[k][n] = [W_ind1|W_rel][k] . Bmat[:,n], 4 lanes per output
__global__ __launch_bounds__(256) void prep2(
    const float* __restrict__ w_ind1, const float* __restrict__ w_rel,
    const float* __restrict__ bmat, float* __restrict__ wbig) {
  int g = blockIdx.x*256 + threadIdx.x;    // 294912 = 73728 outputs x 4 quarters
  int gid = g >> 2, q = g & 3;
  int k = gid / 24, n = gid % 24;
  float a = 0.f;
  if (n != 23) {
    const float* wr = w_rel + (size_t)k*512;
    if (q == 0) {
      const float* w1 = w_ind1 + (size_t)k*128;
#pragma unroll 8
      for (int i = 0; i < 128; ++i) a = fmaf(w1[i], bmat[i*24 + n], a);
#pragma unroll 8
      for (int j = 0; j < 32; ++j) a = fmaf(wr[j], bmat[(128 + j)*24 + n], a);
    } else {
      int j0 = 32 + (q - 1)*160;
#pragma unroll 8
      for (int jj = 0; jj < 160; ++jj) {
        int j = j0 + jj;
        a = fmaf(wr[j], bmat[(128 + j)*24 + n], a);
      }
    }
  }
  a += __shfl_xor(a, 1); a += __shfl_xor(a, 2);
  if (q == 0) wbig[gid] = a;
}

// ---------------- kmain: 64 rows x full K per block; dbuf LDS; 256B-run staging ----------------
// Half-tile = [64 rows][16 float4] (16 KB). Stage instr (w,i): rows w*16+i*4+(l>>4),
// slot l&15 holds source float4 (l&15)^(row&15) -> contiguous 256B per row covered.
// Compute: wave w owns k-stripe [w*16, w*16+16) of each 64-k step; lane = row;
// X from LDS (swizzled b128 reads), W via wave-uniform scalar loads.
__global__ __launch_bounds__(256) void kmain(
    const float* __restrict__ nf, const float* __restrict__ intf,
    const float* __restrict__ wbig, float* __restrict__ ndo, float* __restrict__ relo) {
  __shared__ float4 buf[2][1024];          // 32 KB
  const int tid = threadIdx.x;
  const int l = tid & 63;
  const int w = tid >> 6;
  const int bid = blockIdx.x;
  const bool isNode = bid < 128;

  const int R0 = isNode ? bid*64 : (bid - 128)*64;
  const int nsub = isNode ? 32 : 16;       // K = 2048 / 1024, 64 per step
  float* outp = (isNode ? ndo : relo) + (size_t)R0*23;
  const float* wbu = uniform_ptr(wbig + (size_t)(isNode ? 0 : 2048)*WPITCH + w*16*WPITCH);

  // per-lane stage sources (4 instrs per wave per half-tile)
  const float* src[4];
#pragma unroll
  for (int i = 0; i < 4; ++i) {
    int r = w*16 + i*4 + (l >> 4);
    int grow = R0 + r;
    const float* rp;
    if (isNode) rp = nf + (size_t)grow*2048;
    else {
      int b = grow / 28, p = grow % 28;
      rp = intf + (size_t)(b*64 + d_pi[p]*8 + d_pj[p])*1024;
    }
    src[i] = rp + (((l & 15) ^ (r & 15)) << 2);
  }

  float acc[23];
#pragma unroll
  for (int n = 0; n < 23; ++n) acc[n] = 0.f;

  // prologue: stage half 0
#pragma unroll
  for (int i = 0; i < 4; ++i)
    load_lds16(src[i], (float*)&buf[0][w*256 + i*64]);
  __syncthreads();

#pragma unroll 1
  for (int t = 0; t < nsub; ++t) {
    const int cur = t & 1;
    if (t + 1 < nsub) {                    // issue next half's loads first (latency hides)
#pragma unroll
      for (int i = 0; i < 4; ++i)
        load_lds16(src[i] + (size_t)(t + 1)*64, (float*)&buf[cur ^ 1][w*256 + i*64]);
    }
    // pull this wave's 16 X-floats for its k-stripe (single lgkm mixing point)
    float4 xv[4];
#pragma unroll
    for (int j4 = 0; j4 < 4; ++j4)
      xv[j4] = buf[cur][l*16 + ((w*4 + j4) ^ (l & 15))];
    // pure scalar-load + FMA stretch
    const float* wr0 = wbu + (size_t)t*64*WPITCH;
#pragma unroll
    for (int j4 = 0; j4 < 4; ++j4) {
#pragma unroll
      for (int e = 0; e < 4; ++e) {
        float xs = (e == 0) ? xv[j4].x : (e == 1) ? xv[j4].y : (e == 2) ? xv[j4].z : xv[j4].w;
        const float* wr = wr0 + (j4*4 + e)*WPITCH;
#pragma unroll
        for (int n = 0; n < 23; ++n)
          acc[n] = fmaf(xs, wr[n], acc[n]);
      }
    }
    __syncthreads();                       // drains vm (next half staged) + lgkm; swap
  }

  // cross-wave reduce via LDS (reuse buf), pitch 25 to spread banks
  float* red = (float*)&buf[0][0];
#pragma unroll
  for (int n = 0; n < 23; ++n) red[(w*64 + l)*25 + n] = acc[n];
  __syncthreads();
  for (int g = tid; g < 64*23; g += 256) {
    int r = g / 23, n = g % 23;
    float s = red[r*25 + n] + red[(64 + r)*25 + n] + red[(128 + r)*25 + n] + red[(192 + r)*25 + n];
    outp[(size_t)r*23 + n] = s;
  }
}

// ---------------- kcombine: one batch per block; no partial sums ----------------
__global__ __launch_bounds__(256) void kcombine(
    const float* __restrict__ ndo, const float* __restrict__ relo,
    const float* __restrict__ bbig, const int* __restrict__ opairs,
    float* __restrict__ out) {
  __shared__ float snd[184];
  __shared__ int spos[8];
  int b = blockIdx.x, tid = threadIdx.x;
  if (tid < 184) snd[tid] = ndo[(size_t)b*184 + tid];      // (b*8+o)*23+n
  else if (tid < 192) {
    int r = tid - 184;
    int oi = opairs[b*16 + r*2], oj = opairs[b*16 + r*2 + 1];
    int a = min(oi, oj), bb = max(oi, oj);
    spos[r] = 7*a - (a*(a+1))/2 + bb - 1;
  }
  __syncthreads();
  for (int g = tid; g < 644; g += 256) {
    int p = g / 23, n = g % 23;
    float ed = relo[((size_t)b*28 + p)*23 + n];
    float val = 0.5f*(snd[d_pi[p]*23 + n] + snd[d_pj[p]*23 + n]) + ed + bbig[n];
    int slot = -1, below = 0;
#pragma unroll
    for (int r = 0; r < 8; ++r) {
      int pl = spos[r];
      slot = (pl == p) ? r : slot;
      below += (pl < p) ? 1 : 0;
    }
    if (n == 0) {
      out[OUT_IND + b*28 + p] = 1.f/(1.f + expf(-val));
      out[OUT_LAB + b*28 + p] = (slot >= 0) ? 1.f : 0.f;
    } else {
      int h = n - 1;
      if (slot >= 0) {
        int rr = b*8 + slot;
        if (h < 5)      out[OUT_LRP + rr*5  + h]     = val;
        else if (h < 8) out[OUT_CRP + rr*3  + (h-5)] = val;
        else            out[OUT_MRP + rr*14 + (h-8)] = val;
      } else {
        int s = p - below;
        int rr = b*20 + s;
        if (h < 5)      out[OUT_LRN + rr*5  + h]     = val;
        else if (h < 8) out[OUT_CRN + rr*3  + (h-5)] = val;
        else            out[OUT_MRN + rr*14 + (h-8)] = val;
      }
    }
  }
}

extern "C" void kernel_launch(void* const* d_in, const int* in_sizes, int n_in,
                              void* d_out, int out_size, void* d_ws, size_t ws_size,
                              hipStream_t stream) {
  const float* nf     = (const float*)d_in[0];
  const float* intf   = (const float*)d_in[1];
  const int*   opairs = (const int*)d_in[2];
  const float* w_ind1 = (const float*)d_in[3];
  const float* b_ind1 = (const float*)d_in[4];
  const float* w_ind2 = (const float*)d_in[5];
  const float* b_ind2 = (const float*)d_in[6];
  const float* w_rel  = (const float*)d_in[7];
  const float* b_rel  = (const float*)d_in[8];
  const float* w_cr   = (const float*)d_in[9];
  const float* b_cr   = (const float*)d_in[10];
  const float* w_lr   = (const float*)d_in[11];
  const float* b_lr   = (const float*)d_in[12];
  const float* w_mr   = (const float*)d_in[13];
  const float* b_mr   = (const float*)d_in[14];
  float* out = (float*)d_out;
  float* ws  = (float*)d_ws;

  float* wbig = ws + WS_WBIG;
  float* bmat = ws + WS_BMAT;
  float* bbig = ws + WS_BBIG;
  float* ndo  = ws + WS_ND;
  float* relo = ws + WS_REL;

  prep1<<<177, 256, 0, stream>>>(w_rel, w_ind2, w_lr, w_cr, w_mr,
                                 b_ind1, b_ind2, b_rel, b_lr, b_cr, b_mr, bmat, bbig);
  prep2<<<1152, 256, 0, stream>>>(w_ind1, w_rel, bmat, wbig);
  kmain<<<576, 256, 0, stream>>>(nf, intf, wbig, ndo, relo);
  kcombine<<<1024, 256, 0, stream>>>(ndo, relo, bbig, opairs, out);
}

// Round 6
// 150.422 us; speedup vs baseline: 1.8096x; 1.8096x over previous
//
#include <hip/hip_runtime.h>
#include <cstdint>
#include <cstddef>

#define WPITCH 32            // W_big pitch (floats): 16 rows x 32 = 2048B = 2 stage instrs

// ws layout (float offsets)
#define WS_WBIG 0            // 3072*32 = 98304
#define WS_BMAT 98304        // 640*24  = 15360
#define WS_BBIG 113664       // 24 (+pad to 64)
#define WS_ND   113728       // 8192*23 = 188416
#define WS_REL  302144       // 28672*23 = 659456

// output offsets (floats)
#define OUT_IND 0
#define OUT_LAB 28672
#define OUT_LRP 57344
#define OUT_CRP 98304
#define OUT_MRP 122880
#define OUT_LRN 237568
#define OUT_CRN 339968
#define OUT_MRN 401408

__device__ __constant__ int d_pi[28] = {0,0,0,0,0,0,0,1,1,1,1,1,1,2,2,2,2,2,3,3,3,3,4,4,4,5,5,6};
__device__ __constant__ int d_pj[28] = {1,2,3,4,5,6,7,2,3,4,5,6,7,3,4,5,6,7,4,5,6,7,5,6,7,6,7,7};

__device__ __forceinline__ float wh_at(const float* wlr, const float* wcr, const float* wmr,
                                       int j, int h) {
  return (h < 5) ? wlr[j*5 + h] : (h < 8) ? wcr[j*3 + (h-5)] : wmr[j*14 + (h-8)];
}

// global -> LDS direct (16B per lane); LDS dest = wave-uniform base + lane*16
__device__ __forceinline__ void load_lds16(const float* g, float* l) {
  __builtin_amdgcn_global_load_lds((const __attribute__((address_space(1))) void*)g,
                                   (__attribute__((address_space(3))) void*)l, 16, 0, 0);
}

// ---------------- prep1: Bmat = [T1(128x24); WhE(512x24)] and b_big ----------------
__global__ __launch_bounds__(256) void prep1(
    const float* __restrict__ w_rel, const float* __restrict__ w_ind2,
    const float* __restrict__ w_lr, const float* __restrict__ w_cr, const float* __restrict__ w_mr,
    const float* __restrict__ b_ind1, const float* __restrict__ b_ind2,
    const float* __restrict__ b_rel,
    const float* __restrict__ b_lr, const float* __restrict__ b_cr, const float* __restrict__ b_mr,
    float* __restrict__ bmat, float* __restrict__ bbig) {
  int bid = blockIdx.x, tid = threadIdx.x;
  if (bid < 128) {                         // T1[m][1+h] = sum_j Wrel2[m][j]*Wh[j][h]
    int m = bid;
    __shared__ float swr[512];
    const float* wr2 = w_rel + (size_t)(3072 + m)*512;
    swr[tid]       = wr2[tid];
    swr[tid + 256] = wr2[tid + 256];
    __syncthreads();
    int h = tid >> 3, q = tid & 7;
    if (h < 22) {
      float a = 0.f;
#pragma unroll 8
      for (int jj = 0; jj < 64; ++jj) {
        int j = jj*8 + q;
        a = fmaf(swr[j], wh_at(w_lr, w_cr, w_mr, j, h), a);
      }
      a += __shfl_xor(a, 1); a += __shfl_xor(a, 2); a += __shfl_xor(a, 4);
      if (q == 0) bmat[m*24 + 1 + h] = a;
    }
    if (tid == 248) bmat[m*24 + 0]  = w_ind2[m];
    if (tid == 249) bmat[m*24 + 23] = 0.f;
  } else if (bid == 128) {                 // biases
    __shared__ float sbrel[512];
    for (int j = tid; j < 512; j += 256) {
      float a = b_rel[j];
#pragma unroll 4
      for (int m = 0; m < 128; ++m)
        a = fmaf(b_ind1[m], w_rel[(size_t)(3072 + m)*512 + j], a);
      sbrel[j] = a;
    }
    __syncthreads();
    int h = tid >> 3, q = tid & 7;
    if (h < 22) {
      float bh = (h < 5) ? b_lr[h] : (h < 8) ? b_cr[h-5] : b_mr[h-8];
      float a = 0.f;
#pragma unroll 8
      for (int jj = 0; jj < 64; ++jj) {
        int j = jj*8 + q;
        a = fmaf(sbrel[j], wh_at(w_lr, w_cr, w_mr, j, h), a);
      }
      a += __shfl_xor(a, 1); a += __shfl_xor(a, 2); a += __shfl_xor(a, 4);
      if (q == 0) bbig[1 + h] = a + bh;
    } else if (tid >= 248) {
      int q2 = tid & 7;
      float a = 0.f;
#pragma unroll
      for (int t = 0; t < 16; ++t)
        a = fmaf(b_ind1[q2*16 + t], w_ind2[q2*16 + t], a);
      a += __shfl_xor(a, 1); a += __shfl_xor(a, 2); a += __shfl_xor(a, 4);
      if (tid == 248) bbig[0]  = a + b_ind2[0];
      if (tid == 250) bbig[23] = 0.f;
    }
  } else {                                 // WhE copy: bids 129..176
    int idx = (bid - 129)*256 + tid;
    int j = idx / 24, n = idx % 24;
    float v = (n >= 1 && n <= 22) ? wh_at(w_lr, w_cr, w_mr, j, n - 1) : 0.f;
    bmat[(128 + j)*24 + n] = v;
  }
}

// ---------------- prep2: W_big[k][n] = [W_ind1|W_rel][k] . Bmat[:,n], 4 lanes per output
__global__ __launch_bounds__(256) void prep2(
    const float* __restrict__ w_ind1, const float* __restrict__ w_rel,
    const float* __restrict__ bmat, float* __restrict__ wbig) {
  int g = blockIdx.x*256 + threadIdx.x;    // 294912 = 73728 outputs x 4 quarters
  int gid = g >> 2, q = g & 3;
  int k = gid / 24, n = gid % 24;
  float a = 0.f;
  if (n != 23) {
    const float* wr = w_rel + (size_t)k*512;
    if (q == 0) {
      const float* w1 = w_ind1 + (size_t)k*128;
#pragma unroll 8
      for (int i = 0; i < 128; ++i) a = fmaf(w1[i], bmat[i*24 + n], a);
#pragma unroll 8
      for (int j = 0; j < 32; ++j) a = fmaf(wr[j], bmat[(128 + j)*24 + n], a);
    } else {
      int j0 = 32 + (q - 1)*160;
#pragma unroll 8
      for (int jj = 0; jj < 160; ++jj) {
        int j = j0 + jj;
        a = fmaf(wr[j], bmat[(128 + j)*24 + n], a);
      }
    }
  }
  a += __shfl_xor(a, 1); a += __shfl_xor(a, 2);
  if (q == 0) wbig[(size_t)k*WPITCH + n] = a;   // pitch-32 for 2048B stripe staging
}

// ---------------- kmain: 64 rows x full K per block; X AND W staged to LDS ----------------
// Step = 64 k. X half-tile [64 rows][16 float4] (16KB), W half [4 waves][16k][32] (8KB).
// Wave w: stages X rows w*16..+16 and its own W stripe; computes k-stripe w*16..+16 for
// all 64 rows (lane = row). W read as same-address broadcast ds_reads (conflict-free).
__global__ __launch_bounds__(256) void kmain(
    const float* __restrict__ nf, const float* __restrict__ intf,
    const float* __restrict__ wbig, float* __restrict__ ndo, float* __restrict__ relo) {
  __shared__ float smem[12288];            // 48 KB: X dbuf 2x4096, W dbuf 2x2048 @8192
  const int tid = threadIdx.x;
  const int l = tid & 63;
  const int w = tid >> 6;
  const int bid = blockIdx.x;
  const bool isNode = bid < 128;

  const int R0 = isNode ? bid*64 : (bid - 128)*64;
  const int nsub = isNode ? 32 : 16;       // K = 2048 / 1024, 64 k per step
  float* outp = (isNode ? ndo : relo) + (size_t)R0*23;
  const float* wsrc0 = wbig + (size_t)(isNode ? 0 : 2048)*WPITCH + w*16*WPITCH;

  // X stage sources (4 instrs per wave per half): instr i covers rows w*16+i*4..+4,
  // lane l -> row +(l>>4), slot l&15 holds source float4 (l&15)^(row&15).
  const float* src[4];
#pragma unroll
  for (int i = 0; i < 4; ++i) {
    int r = w*16 + i*4 + (l >> 4);
    int grow = R0 + r;
    const float* rp;
    if (isNode) rp = nf + (size_t)grow*2048;
    else {
      int b = grow / 28, p = grow % 28;
      rp = intf + (size_t)(b*64 + d_pi[p]*8 + d_pj[p])*1024;
    }
    src[i] = rp + (((l & 15) ^ (r & 15)) << 2);
  }

  float acc[23];
#pragma unroll
  for (int n = 0; n < 23; ++n) acc[n] = 0.f;

  // prologue: stage half 0 (X + W)
#pragma unroll
  for (int i = 0; i < 4; ++i)
    load_lds16(src[i], smem + (w*256 + i*64)*4);
  load_lds16(wsrc0 + l*4,       smem + 8192 + w*512);
  load_lds16(wsrc0 + 256 + l*4, smem + 8192 + w*512 + 256);
  __syncthreads();

#pragma unroll 1
  for (int t = 0; t < nsub; ++t) {
    const int cur = t & 1;
    if (t + 1 < nsub) {                    // issue next half's loads first (latency hides)
      const int nx = cur ^ 1;
#pragma unroll
      for (int i = 0; i < 4; ++i)
        load_lds16(src[i] + (size_t)(t + 1)*64, smem + nx*4096 + (w*256 + i*64)*4);
      const float* wsrc = wsrc0 + (size_t)(t + 1)*64*WPITCH;
      load_lds16(wsrc + l*4,       smem + 8192 + nx*2048 + w*512);
      load_lds16(wsrc + 256 + l*4, smem + 8192 + nx*2048 + w*512 + 256);
    }
    const float4* bx = (const float4*)(smem + cur*4096);
    const float*  wl = smem + 8192 + cur*2048 + w*512;   // this wave's [16][32] stripe
#pragma unroll
    for (int k4 = 0; k4 < 4; ++k4) {
      float4 x = bx[l*16 + ((w*4 + k4) ^ (l & 15))];
#pragma unroll
      for (int e = 0; e < 4; ++e) {
        float xs = (e == 0) ? x.x : (e == 1) ? x.y : (e == 2) ? x.z : x.w;
        const float* wr = wl + (k4*4 + e)*32;            // broadcast (uniform addr)
#pragma unroll
        for (int n = 0; n < 23; ++n)
          acc[n] = fmaf(xs, wr[n], acc[n]);
      }
    }
    __syncthreads();                       // drains vm (next half staged) + lgkm; swap
  }

  // cross-wave reduce via LDS (pitch 25), then coalesced store
  float* red = smem;
#pragma unroll
  for (int n = 0; n < 23; ++n) red[(w*64 + l)*25 + n] = acc[n];
  __syncthreads();
  for (int g = tid; g < 64*23; g += 256) {
    int r = g / 23, n = g % 23;
    float s = red[r*25 + n] + red[(64 + r)*25 + n] + red[(128 + r)*25 + n] + red[(192 + r)*25 + n];
    outp[(size_t)r*23 + n] = s;
  }
}

// ---------------- kcombine: one batch per block ----------------
__global__ __launch_bounds__(256) void kcombine(
    const float* __restrict__ ndo, const float* __restrict__ relo,
    const float* __restrict__ bbig, const int* __restrict__ opairs,
    float* __restrict__ out) {
  __shared__ float snd[184];
  __shared__ int spos[8];
  int b = blockIdx.x, tid = threadIdx.x;
  if (tid < 184) snd[tid] = ndo[(size_t)b*184 + tid];      // (b*8+o)*23+n
  else if (tid < 192) {
    int r = tid - 184;
    int oi = opairs[b*16 + r*2], oj = opairs[b*16 + r*2 + 1];
    int a = min(oi, oj), bb = max(oi, oj);
    spos[r] = 7*a - (a*(a+1))/2 + bb - 1;
  }
  __syncthreads();
  for (int g = tid; g < 644; g += 256) {
    int p = g / 23, n = g % 23;
    float ed = relo[((size_t)b*28 + p)*23 + n];
    float val = 0.5f*(snd[d_pi[p]*23 + n] + snd[d_pj[p]*23 + n]) + ed + bbig[n];
    int slot = -1, below = 0;
#pragma unroll
    for (int r = 0; r < 8; ++r) {
      int pl = spos[r];
      slot = (pl == p) ? r : slot;
      below += (pl < p) ? 1 : 0;
    }
    if (n == 0) {
      out[OUT_IND + b*28 + p] = 1.f/(1.f + expf(-val));
      out[OUT_LAB + b*28 + p] = (slot >= 0) ? 1.f : 0.f;
    } else {
      int h = n - 1;
      if (slot >= 0) {
        int rr = b*8 + slot;
        if (h < 5)      out[OUT_LRP + rr*5  + h]     = val;
        else if (h < 8) out[OUT_CRP + rr*3  + (h-5)] = val;
        else            out[OUT_MRP + rr*14 + (h-8)] = val;
      } else {
        int s = p - below;
        int rr = b*20 + s;
        if (h < 5)      out[OUT_LRN + rr*5  + h]     = val;
        else if (h < 8) out[OUT_CRN + rr*3  + (h-5)] = val;
        else            out[OUT_MRN + rr*14 + (h-8)] = val;
      }
    }
  }
}

extern "C" void kernel_launch(void* const* d_in, const int* in_sizes, int n_in,
                              void* d_out, int out_size, void* d_ws, size_t ws_size,
                              hipStream_t stream) {
  const float* nf     = (const float*)d_in[0];
  const float* intf   = (const float*)d_in[1];
  const int*   opairs = (const int*)d_in[2];
  const float* w_ind1 = (const float*)d_in[3];
  const float* b_ind1 = (const float*)d_in[4];
  const float* w_ind2 = (const float*)d_in[5];
  const float* b_ind2 = (const float*)d_in[6];
  const float* w_rel  = (const float*)d_in[7];
  const float* b_rel  = (const float*)d_in[8];
  const float* w_cr   = (const float*)d_in[9];
  const float* b_cr   = (const float*)d_in[10];
  const float* w_lr   = (const float*)d_in[11];
  const float* b_lr   = (const float*)d_in[12];
  const float* w_mr   = (const float*)d_in[13];
  const float* b_mr   = (const float*)d_in[14];
  float* out = (float*)d_out;
  float* ws  = (float*)d_ws;

  float* wbig = ws + WS_WBIG;
  float* bmat = ws + WS_BMAT;
  float* bbig = ws + WS_BBIG;
  float* ndo  = ws + WS_ND;
  float* relo = ws + WS_REL;

  prep1<<<177, 256, 0, stream>>>(w_rel, w_ind2, w_lr, w_cr, w_mr,
                                 b_ind1, b_ind2, b_rel, b_lr, b_cr, b_mr, bmat, bbig);
  prep2<<<1152, 256, 0, stream>>>(w_ind1, w_rel, bmat, wbig);
  kmain<<<576, 256, 0, stream>>>(nf, intf, wbig, ndo, relo);
  kcombine<<<1024, 256, 0, stream>>>(ndo, relo, bbig, opairs, out);
}

// Round 7
// 144.462 us; speedup vs baseline: 1.8842x; 1.0413x over previous
//
#include <hip/hip_runtime.h>
#include <cstdint>
#include <cstddef>

#define WPITCH 32            // W_big pitch (floats): 16 k x 32 = 2048B = 2 stage instrs/wave

// ws layout (float offsets)
#define WS_WBIG 0            // 3072*32 = 98304
#define WS_BMAT 98304        // bmatT: 24*640 = 15360
#define WS_BBIG 113664       // 24 (+pad to 64)
#define WS_ND   113728       // 8192*23 = 188416
#define WS_REL  302144       // 28672*23 = 659456

// output offsets (floats)
#define OUT_IND 0
#define OUT_LAB 28672
#define OUT_LRP 57344
#define OUT_CRP 98304
#define OUT_MRP 122880
#define OUT_LRN 237568
#define OUT_CRN 339968
#define OUT_MRN 401408

__device__ __constant__ int d_pi[28] = {0,0,0,0,0,0,0,1,1,1,1,1,1,2,2,2,2,2,3,3,3,3,4,4,4,5,5,6};
__device__ __constant__ int d_pj[28] = {1,2,3,4,5,6,7,2,3,4,5,6,7,3,4,5,6,7,4,5,6,7,5,6,7,6,7,7};

__device__ __forceinline__ float wh_at(const float* wlr, const float* wcr, const float* wmr,
                                       int j, int h) {
  return (h < 5) ? wlr[j*5 + h] : (h < 8) ? wcr[j*3 + (h-5)] : wmr[j*14 + (h-8)];
}

// global -> LDS direct (16B per lane); LDS dest = wave-uniform base + lane*16
__device__ __forceinline__ void load_lds16(const float* g, float* l) {
  __builtin_amdgcn_global_load_lds((const __attribute__((address_space(1))) void*)g,
                                   (__attribute__((address_space(3))) void*)l, 16, 0, 0);
}

// ---------------- prep1: bmatT[24][640] = [T1(128) | WhE(512)]^T rows, and b_big ----------------
__global__ __launch_bounds__(256) void prep1(
    const float* __restrict__ w_rel, const float* __restrict__ w_ind2,
    const float* __restrict__ w_lr, const float* __restrict__ w_cr, const float* __restrict__ w_mr,
    const float* __restrict__ b_ind1, const float* __restrict__ b_ind2,
    const float* __restrict__ b_rel,
    const float* __restrict__ b_lr, const float* __restrict__ b_cr, const float* __restrict__ b_mr,
    float* __restrict__ bmat, float* __restrict__ bbig) {
  int bid = blockIdx.x, tid = threadIdx.x;
  if (bid < 128) {                         // T1 col m: bmatT[1+h][m] = sum_j Wrel2[m][j]*Wh[j][h]
    int m = bid;
    __shared__ float swr[512];
    const float* wr2 = w_rel + (size_t)(3072 + m)*512;
    swr[tid]       = wr2[tid];
    swr[tid + 256] = wr2[tid + 256];
    __syncthreads();
    int h = tid >> 3, q = tid & 7;
    if (h < 22) {
      float a = 0.f;
#pragma unroll 8
      for (int jj = 0; jj < 64; ++jj) {
        int j = jj*8 + q;
        a = fmaf(swr[j], wh_at(w_lr, w_cr, w_mr, j, h), a);
      }
      a += __shfl_xor(a, 1); a += __shfl_xor(a, 2); a += __shfl_xor(a, 4);
      if (q == 0) bmat[(1 + h)*640 + m] = a;
    }
    if (tid == 248) bmat[0*640 + m]  = w_ind2[m];
    if (tid == 249) bmat[23*640 + m] = 0.f;
  } else if (bid == 128) {                 // biases
    __shared__ float sbrel[512];
    for (int j = tid; j < 512; j += 256) {
      float a = b_rel[j];
#pragma unroll 4
      for (int m = 0; m < 128; ++m)
        a = fmaf(b_ind1[m], w_rel[(size_t)(3072 + m)*512 + j], a);
      sbrel[j] = a;
    }
    __syncthreads();
    int h = tid >> 3, q = tid & 7;
    if (h < 22) {
      float bh = (h < 5) ? b_lr[h] : (h < 8) ? b_cr[h-5] : b_mr[h-8];
      float a = 0.f;
#pragma unroll 8
      for (int jj = 0; jj < 64; ++jj) {
        int j = jj*8 + q;
        a = fmaf(sbrel[j], wh_at(w_lr, w_cr, w_mr, j, h), a);
      }
      a += __shfl_xor(a, 1); a += __shfl_xor(a, 2); a += __shfl_xor(a, 4);
      if (q == 0) bbig[1 + h] = a + bh;
    } else if (tid >= 248) {
      int q2 = tid & 7;
      float a = 0.f;
#pragma unroll
      for (int t = 0; t < 16; ++t)
        a = fmaf(b_ind1[q2*16 + t], w_ind2[q2*16 + t], a);
      a += __shfl_xor(a, 1); a += __shfl_xor(a, 2); a += __shfl_xor(a, 4);
      if (tid == 248) bbig[0]  = a + b_ind2[0];
      if (tid == 250) bbig[23] = 0.f;
    }
  } else {                                 // WhE: bmatT[n][128+j], bids 129..176
    int idx = (bid - 129)*256 + tid;
    int j = idx / 24, n = idx % 24;
    float v = (n >= 1 && n <= 22) ? wh_at(w_lr, w_cr, w_mr, j, n - 1) : 0.f;
    bmat[n*640 + 128 + j] = v;
  }
}

// ---------------- prep2: W_big[k][n] = [W_ind1|W_rel][k] . bmatT[n][:], 4 lanes per output
__global__ __launch_bounds__(256) void prep2(
    const float* __restrict__ w_ind1, const float* __restrict__ w_rel,
    const float* __restrict__ bmat, float* __restrict__ wbig) {
  int g = blockIdx.x*256 + threadIdx.x;    // 294912 = 73728 outputs x 4 quarters
  int gid = g >> 2, q = g & 3;
  int k = gid / 24, n = gid % 24;
  float a = 0.f;
  if (n != 23) {
    const float* wr = w_rel + (size_t)k*512;
    const float* bn = bmat + n*640;        // contiguous per-thread stream
    if (q == 0) {
      const float* w1 = w_ind1 + (size_t)k*128;
#pragma unroll 8
      for (int i = 0; i < 128; ++i) a = fmaf(w1[i], bn[i], a);
#pragma unroll 8
      for (int j = 0; j < 32; ++j) a = fmaf(wr[j], bn[128 + j], a);
    } else {
      int j0 = 32 + (q - 1)*160;
#pragma unroll 8
      for (int jj = 0; jj < 160; ++jj) {
        int j = j0 + jj;
        a = fmaf(wr[j], bn[128 + j], a);
      }
    }
  }
  a += __shfl_xor(a, 1); a += __shfl_xor(a, 2);
  if (q == 0) wbig[(size_t)k*WPITCH + n] = a;   // pitch-32 for stripe staging
}

// ---------------- kmain: 64 rows x full K per block; 3-buffer ring, counted vmcnt ----------------
// Step = 64 k. Buffer d: X [64 rows][16 float4] (16KB) + W [4 waves][16k][32] (8KB) = 24KB; x3 = 72KB.
// Per step each wave issues 6 global_load_lds (4 X + 2 W) for step t+2; waits vmcnt(6) for
// step t (t+1 stays in flight -> never drain in main loop); raw s_barrier (no implicit drain).
__global__ __launch_bounds__(256) void kmain(
    const float* __restrict__ nf, const float* __restrict__ intf,
    const float* __restrict__ wbig, float* __restrict__ ndo, float* __restrict__ relo) {
  __shared__ float smem[18432];            // 72 KB
  const int tid = threadIdx.x;
  const int l = tid & 63;
  const int w = tid >> 6;
  const int bid = blockIdx.x;
  const bool isNode = bid < 128;

  const int R0 = isNode ? bid*64 : (bid - 128)*64;
  const int nsub = isNode ? 32 : 16;       // K = 2048 / 1024, 64 k per step
  float* outp = (isNode ? ndo : relo) + (size_t)R0*23;
  const float* wsrc0 = wbig + (size_t)(isNode ? 0 : 2048)*WPITCH + w*16*WPITCH;

  // X stage sources: instr i covers rows w*16+i*4..+4; lane l -> row +(l>>4),
  // slot l&15 holds source float4 (l&15)^(row&15)  (contiguous 256B per row).
  const float* src[4];
#pragma unroll
  for (int i = 0; i < 4; ++i) {
    int r = w*16 + i*4 + (l >> 4);
    int grow = R0 + r;
    const float* rp;
    if (isNode) rp = nf + (size_t)grow*2048;
    else {
      int b = grow / 28, p = grow % 28;
      rp = intf + (size_t)(b*64 + d_pi[p]*8 + d_pj[p])*1024;
    }
    src[i] = rp + (((l & 15) ^ (r & 15)) << 2);
  }

  float acc[23];
#pragma unroll
  for (int n = 0; n < 23; ++n) acc[n] = 0.f;

  // prologue: issue steps 0 and 1 (12 loads in flight per wave)
#pragma unroll
  for (int d = 0; d < 2; ++d) {
    float* bd = smem + d*6144;
#pragma unroll
    for (int i = 0; i < 4; ++i)
      load_lds16(src[i] + (size_t)d*64, bd + (w*256 + i*64)*4);
    const float* wsrc = wsrc0 + (size_t)d*64*WPITCH;
    load_lds16(wsrc + l*4,       bd + 4096 + w*512);
    load_lds16(wsrc + 256 + l*4, bd + 4096 + w*512 + 256);
  }

#pragma unroll 1
  for (int t = 0; t < nsub; ++t) {
    // wait for step t's 6 loads (t+1's 6 remain in flight); last step drains
    if (t + 1 < nsub) asm volatile("s_waitcnt vmcnt(6)" ::: "memory");
    else              asm volatile("s_waitcnt vmcnt(0)" ::: "memory");
    __builtin_amdgcn_s_barrier();          // raw barrier: no implicit vm drain

    if (t + 2 < nsub) {                    // issue step t+2 into buf (t+2)%3 (all waves done reading it)
      float* bd = smem + ((t + 2) % 3)*6144;
#pragma unroll
      for (int i = 0; i < 4; ++i)
        load_lds16(src[i] + (size_t)(t + 2)*64, bd + (w*256 + i*64)*4);
      const float* wsrc = wsrc0 + (size_t)(t + 2)*64*WPITCH;
      load_lds16(wsrc + l*4,       bd + 4096 + w*512);
      load_lds16(wsrc + 256 + l*4, bd + 4096 + w*512 + 256);
    }

    const float4* bx = (const float4*)(smem + (t % 3)*6144);
    const float*  wl = smem + (t % 3)*6144 + 4096 + w*512;  // this wave's [16][32] stripe
#pragma unroll
    for (int k4 = 0; k4 < 4; ++k4) {
      float4 x = bx[l*16 + ((w*4 + k4) ^ (l & 15))];
#pragma unroll
      for (int e = 0; e < 4; ++e) {
        float xs = (e == 0) ? x.x : (e == 1) ? x.y : (e == 2) ? x.z : x.w;
        const float* wr = wl + (k4*4 + e)*32;               // broadcast (uniform addr)
#pragma unroll
        for (int n = 0; n < 23; ++n)
          acc[n] = fmaf(xs, wr[n], acc[n]);
      }
    }
  }

  // epilogue: cross-wave reduce via LDS (pitch 25) -> coalesced store
  __syncthreads();                         // all waves done computing before smem reuse
  float* red = smem;
#pragma unroll
  for (int n = 0; n < 23; ++n) red[(w*64 + l)*25 + n] = acc[n];
  __syncthreads();
  for (int g = tid; g < 64*23; g += 256) {
    int r = g / 23, n = g % 23;
    float s = red[r*25 + n] + red[(64 + r)*25 + n] + red[(128 + r)*25 + n] + red[(192 + r)*25 + n];
    outp[(size_t)r*23 + n] = s;
  }
}

// ---------------- kcombine: one batch per block ----------------
__global__ __launch_bounds__(256) void kcombine(
    const float* __restrict__ ndo, const float* __restrict__ relo,
    const float* __restrict__ bbig, const int* __restrict__ opairs,
    float* __restrict__ out) {
  __shared__ float snd[184];
  __shared__ int spos[8];
  int b = blockIdx.x, tid = threadIdx.x;
  if (tid < 184) snd[tid] = ndo[(size_t)b*184 + tid];      // (b*8+o)*23+n
  else if (tid < 192) {
    int r = tid - 184;
    int oi = opairs[b*16 + r*2], oj = opairs[b*16 + r*2 + 1];
    int a = min(oi, oj), bb = max(oi, oj);
    spos[r] = 7*a - (a*(a+1))/2 + bb - 1;
  }
  __syncthreads();
  for (int g = tid; g < 644; g += 256) {
    int p = g / 23, n = g % 23;
    float ed = relo[((size_t)b*28 + p)*23 + n];
    float val = 0.5f*(snd[d_pi[p]*23 + n] + snd[d_pj[p]*23 + n]) + ed + bbig[n];
    int slot = -1, below = 0;
#pragma unroll
    for (int r = 0; r < 8; ++r) {
      int pl = spos[r];
      slot = (pl == p) ? r : slot;
      below += (pl < p) ? 1 : 0;
    }
    if (n == 0) {
      out[OUT_IND + b*28 + p] = 1.f/(1.f + expf(-val));
      out[OUT_LAB + b*28 + p] = (slot >= 0) ? 1.f : 0.f;
    } else {
      int h = n - 1;
      if (slot >= 0) {
        int rr = b*8 + slot;
        if (h < 5)      out[OUT_LRP + rr*5  + h]     = val;
        else if (h < 8) out[OUT_CRP + rr*3  + (h-5)] = val;
        else            out[OUT_MRP + rr*14 + (h-8)] = val;
      } else {
        int s = p - below;
        int rr = b*20 + s;
        if (h < 5)      out[OUT_LRN + rr*5  + h]     = val;
        else if (h < 8) out[OUT_CRN + rr*3  + (h-5)] = val;
        else            out[OUT_MRN + rr*14 + (h-8)] = val;
      }
    }
  }
}

extern "C" void kernel_launch(void* const* d_in, const int* in_sizes, int n_in,
                              void* d_out, int out_size, void* d_ws, size_t ws_size,
                              hipStream_t stream) {
  const float* nf     = (const float*)d_in[0];
  const float* intf   = (const float*)d_in[1];
  const int*   opairs = (const int*)d_in[2];
  const float* w_ind1 = (const float*)d_in[3];
  const float* b_ind1 = (const float*)d_in[4];
  const float* w_ind2 = (const float*)d_in[5];
  const float* b_ind2 = (const float*)d_in[6];
  const float* w_rel  = (const float*)d_in[7];
  const float* b_rel  = (const float*)d_in[8];
  const float* w_cr   = (const float*)d_in[9];
  const float* b_cr   = (const float*)d_in[10];
  const float* w_lr   = (const float*)d_in[11];
  const float* b_lr   = (const float*)d_in[12];
  const float* w_mr   = (const float*)d_in[13];
  const float* b_mr   = (const float*)d_in[14];
  float* out = (float*)d_out;
  float* ws  = (float*)d_ws;

  float* wbig = ws + WS_WBIG;
  float* bmat = ws + WS_BMAT;
  float* bbig = ws + WS_BBIG;
  float* ndo  = ws + WS_ND;
  float* relo = ws + WS_REL;

  prep1<<<177, 256, 0, stream>>>(w_rel, w_ind2, w_lr, w_cr, w_mr,
                                 b_ind1, b_ind2, b_rel, b_lr, b_cr, b_mr, bmat, bbig);
  prep2<<<1152, 256, 0, stream>>>(w_ind1, w_rel, bmat, wbig);
  kmain<<<576, 256, 0, stream>>>(nf, intf, wbig, ndo, relo);
  kcombine<<<1024, 256, 0, stream>>>(ndo, relo, bbig, opairs, out);
}

// Round 8
// 141.259 us; speedup vs baseline: 1.9269x; 1.0227x over previous
//
#include <hip/hip_runtime.h>
#include <cstdint>
#include <cstddef>

// ws layout (float offsets)
#define WS_WBIG 0            // 3072*32 = 98304
#define WS_BMAT 98304        // bmatT: 24*640 = 15360
#define WS_BBIG 113664       // 24 (+pad to 64)
#define WS_ND   113728       // 4*8192*23 = 753664
#define WS_ED   867392       // 4*28672*23 = 2637824

// output offsets (floats)
#define OUT_IND 0
#define OUT_LAB 28672
#define OUT_LRP 57344
#define OUT_CRP 98304
#define OUT_MRP 122880
#define OUT_LRN 237568
#define OUT_CRN 339968
#define OUT_MRN 401408

__device__ __constant__ int d_pi[28] = {0,0,0,0,0,0,0,1,1,1,1,1,1,2,2,2,2,2,3,3,3,3,4,4,4,5,5,6};
__device__ __constant__ int d_pj[28] = {1,2,3,4,5,6,7,2,3,4,5,6,7,3,4,5,6,7,4,5,6,7,5,6,7,6,7,7};

__device__ __forceinline__ float wh_at(const float* wlr, const float* wcr, const float* wmr,
                                       int j, int h) {
  return (h < 5) ? wlr[j*5 + h] : (h < 8) ? wcr[j*3 + (h-5)] : wmr[j*14 + (h-8)];
}

// global -> LDS direct (16B per lane); LDS dest = wave-uniform base + lane*16
__device__ __forceinline__ void load_lds16(const float* g, float* l) {
  __builtin_amdgcn_global_load_lds((const __attribute__((address_space(1))) void*)g,
                                   (__attribute__((address_space(3))) void*)l, 16, 0, 0);
}

// ---------------- prep1: bmatT[24][640] and b_big ----------------
__global__ __launch_bounds__(256) void prep1(
    const float* __restrict__ w_rel, const float* __restrict__ w_ind2,
    const float* __restrict__ w_lr, const float* __restrict__ w_cr, const float* __restrict__ w_mr,
    const float* __restrict__ b_ind1, const float* __restrict__ b_ind2,
    const float* __restrict__ b_rel,
    const float* __restrict__ b_lr, const float* __restrict__ b_cr, const float* __restrict__ b_mr,
    float* __restrict__ bmat, float* __restrict__ bbig) {
  int bid = blockIdx.x, tid = threadIdx.x;
  if (bid < 128) {                         // T1 col m: bmatT[1+h][m] = sum_j Wrel2[m][j]*Wh[j][h]
    int m = bid;
    __shared__ float swr[512];
    const float* wr2 = w_rel + (size_t)(3072 + m)*512;
    swr[tid]       = wr2[tid];
    swr[tid + 256] = wr2[tid + 256];
    __syncthreads();
    int h = tid >> 3, q = tid & 7;
    if (h < 22) {
      float a = 0.f;
#pragma unroll 8
      for (int jj = 0; jj < 64; ++jj) {
        int j = jj*8 + q;
        a = fmaf(swr[j], wh_at(w_lr, w_cr, w_mr, j, h), a);
      }
      a += __shfl_xor(a, 1); a += __shfl_xor(a, 2); a += __shfl_xor(a, 4);
      if (q == 0) bmat[(1 + h)*640 + m] = a;
    }
    if (tid == 248) bmat[0*640 + m]  = w_ind2[m];
    if (tid == 249) bmat[23*640 + m] = 0.f;
  } else if (bid == 128) {                 // biases
    __shared__ float sbrel[512];
    for (int j = tid; j < 512; j += 256) {
      float a = b_rel[j];
#pragma unroll 4
      for (int m = 0; m < 128; ++m)
        a = fmaf(b_ind1[m], w_rel[(size_t)(3072 + m)*512 + j], a);
      sbrel[j] = a;
    }
    __syncthreads();
    int h = tid >> 3, q = tid & 7;
    if (h < 22) {
      float bh = (h < 5) ? b_lr[h] : (h < 8) ? b_cr[h-5] : b_mr[h-8];
      float a = 0.f;
#pragma unroll 8
      for (int jj = 0; jj < 64; ++jj) {
        int j = jj*8 + q;
        a = fmaf(sbrel[j], wh_at(w_lr, w_cr, w_mr, j, h), a);
      }
      a += __shfl_xor(a, 1); a += __shfl_xor(a, 2); a += __shfl_xor(a, 4);
      if (q == 0) bbig[1 + h] = a + bh;
    } else if (tid >= 248) {
      int q2 = tid & 7;
      float a = 0.f;
#pragma unroll
      for (int t = 0; t < 16; ++t)
        a = fmaf(b_ind1[q2*16 + t], w_ind2[q2*16 + t], a);
      a += __shfl_xor(a, 1); a += __shfl_xor(a, 2); a += __shfl_xor(a, 4);
      if (tid == 248) bbig[0]  = a + b_ind2[0];
      if (tid == 250) bbig[23] = 0.f;
    }
  } else {                                 // WhE: bmatT[n][128+j], bids 129..176
    int idx = (bid - 129)*256 + tid;
    int j = idx / 24, n = idx % 24;
    float v = (n >= 1 && n <= 22) ? wh_at(w_lr, w_cr, w_mr, j, n - 1) : 0.f;
    bmat[n*640 + 128 + j] = v;
  }
}

// ---------------- prep2: W_big[k][n] (pitch 32) = [W_ind1|W_rel][k] . bmatT[n][:]
__global__ __launch_bounds__(256) void prep2(
    const float* __restrict__ w_ind1, const float* __restrict__ w_rel,
    const float* __restrict__ bmat, float* __restrict__ wbig) {
  int g = blockIdx.x*256 + threadIdx.x;    // 294912 = 73728 outputs x 4 quarters
  int gid = g >> 2, q = g & 3;
  int k = gid / 24, n = gid % 24;
  float a = 0.f;
  if (n != 23) {
    const float* wr = w_rel + (size_t)k*512;
    const float* bn = bmat + n*640;
    if (q == 0) {
      const float* w1 = w_ind1 + (size_t)k*128;
#pragma unroll 8
      for (int i = 0; i < 128; ++i) a = fmaf(w1[i], bn[i], a);
#pragma unroll 8
      for (int j = 0; j < 32; ++j) a = fmaf(wr[j], bn[128 + j], a);
    } else {
      int j0 = 32 + (q - 1)*160;
#pragma unroll 8
      for (int jj = 0; jj < 160; ++jj) {
        int j = j0 + jj;
        a = fmaf(wr[j], bn[128 + j], a);
      }
    }
  }
  a += __shfl_xor(a, 1); a += __shfl_xor(a, 2);
  if (q == 0) wbig[(size_t)k*32 + n] = a;
}

// ---------------- kmain: 256 rows x K-chunk per block; lane = 4 rows; wave = 16-k substripe ----
// Step = 64 k. Buffer d (18432 floats): X [256 rows][16 float4] (64KB) + W [4 waves][16k][32] (8KB).
// Lane l owns rows {l, l+64, l+128, l+192} (row&7 = l&7 -> XOR swizzle bank-bijective).
// W read once per k per lane (6 b128 broadcast) -> feeds 92 FMAs (4 rows x 23).
__global__ __launch_bounds__(256, 1) void kmain(
    const float* __restrict__ nf, const float* __restrict__ intf,
    const float* __restrict__ wbig, float* __restrict__ ndp, float* __restrict__ edp) {
  __shared__ float smem[36864];            // 144 KB: two 18432-float buffers
  const int tid = threadIdx.x;
  const int l = tid & 63;
  const int w = tid >> 6;
  const int bid = blockIdx.x;
  const bool isNode = bid < 128;

  int chunk, R0, kd0, nsteps;
  if (isNode) { chunk = bid & 3;  R0 = (bid >> 2)*256;         kd0 = chunk*512; nsteps = 8; }
  else        { int eb = bid-128; chunk = eb & 3; R0 = (eb >> 2)*256; kd0 = chunk*256; nsteps = 4; }

  // X stage sources: wave w stages rows [w*64, w*64+64): instr i covers rows w*64+i*4..+4;
  // lane l -> row +(l>>4), slot l&15; source slot pre-swizzled by (row&7).
  const float* xsrc[16];
  {
    int sr = l >> 4, slot = l & 15;
#pragma unroll
    for (int i = 0; i < 16; ++i) {
      int r = w*64 + i*4 + sr;
      int grow = R0 + r;
      const float* rp;
      if (isNode) rp = nf + (size_t)grow*2048;
      else {
        int b = grow / 28, p = grow % 28;
        rp = intf + (size_t)(b*64 + d_pi[p]*8 + d_pj[p])*1024;
      }
      xsrc[i] = rp + kd0 + ((slot ^ (r & 7)) << 2);
    }
  }
  // W stage source: wave w stages its substripe [w*16, w*16+16) x pitch 32 = 512 floats = 2 instrs
  const float* wsrc = wbig + ((size_t)(isNode ? 0 : 2048) + kd0 + w*16)*32 + (l << 2);

  float acc[4][23];
#pragma unroll
  for (int j = 0; j < 4; ++j)
#pragma unroll
    for (int n = 0; n < 23; ++n) acc[j][n] = 0.f;

  // stage helper: 16 X + 2 W = 18 global_load_lds per wave per step
#define STAGE(T, D) do {                                                        \
    float* bd = smem + (D)*18432;                                               \
    _Pragma("unroll")                                                           \
    for (int i = 0; i < 16; ++i)                                                \
      load_lds16(xsrc[i] + (size_t)(T)*64, bd + (w*64 + i*4)*64);               \
    load_lds16(wsrc + (size_t)(T)*2048,       bd + 16384 + w*512);              \
    load_lds16(wsrc + (size_t)(T)*2048 + 256, bd + 16384 + w*512 + 256);        \
  } while (0)

  STAGE(0, 0);                              // prologue

  const int sl = l & 7;                     // read-side swizzle (same for all 4 owned rows)
#pragma unroll 1
  for (int t = 0; t < nsteps; ++t) {
    __builtin_amdgcn_s_barrier();           // all waves finished compute t-1 -> buf (t+1)&1 free
    if (t + 1 < nsteps) {
      STAGE(t + 1, (t + 1) & 1);
      asm volatile("s_waitcnt vmcnt(18)" ::: "memory");   // step t's 18 landed; t+1 in flight
    } else {
      asm volatile("s_waitcnt vmcnt(0)" ::: "memory");
    }

    const float4* bx = (const float4*)(smem + (t & 1)*18432);
    const float*  wl = smem + (t & 1)*18432 + 16384 + w*512;
#pragma unroll
    for (int k4 = 0; k4 < 4; ++k4) {
      float4 xr[4];
#pragma unroll
      for (int j = 0; j < 4; ++j)
        xr[j] = bx[(l + 64*j)*16 + ((w*4 + k4) ^ sl)];
#pragma unroll
      for (int e = 0; e < 4; ++e) {
        const float4* wv = (const float4*)(wl + (k4*4 + e)*32);
        float wreg[24];
#pragma unroll
        for (int v4 = 0; v4 < 6; ++v4) {
          float4 t4 = wv[v4];
          wreg[v4*4+0] = t4.x; wreg[v4*4+1] = t4.y; wreg[v4*4+2] = t4.z; wreg[v4*4+3] = t4.w;
        }
#pragma unroll
        for (int j = 0; j < 4; ++j) {
          float xs = (e == 0) ? xr[j].x : (e == 1) ? xr[j].y : (e == 2) ? xr[j].z : xr[j].w;
#pragma unroll
          for (int n = 0; n < 23; ++n)
            acc[j][n] = fmaf(xs, wreg[n], acc[j][n]);
        }
      }
    }
  }
#undef STAGE

  // cross-wave reduce: wave w's partials for all 256 rows -> quadrant w (pitch 25)
  __syncthreads();
  float* red = smem;
#pragma unroll
  for (int j = 0; j < 4; ++j)
#pragma unroll
    for (int n = 0; n < 23; ++n)
      red[(w*256 + l + 64*j)*25 + n] = acc[j][n];
  __syncthreads();

  float* outp = isNode ? (ndp + ((size_t)chunk*8192  + R0)*23)
                       : (edp + ((size_t)chunk*28672 + R0)*23);
  for (int g = tid; g < 256*23; g += 256) {
    int r = g / 23, n = g - r*23;
    float s = red[r*25 + n] + red[(256 + r)*25 + n] + red[(512 + r)*25 + n] + red[(768 + r)*25 + n];
    outp[g] = s;
  }
}

// ---------------- kcombine: one batch per block; sums 4 K-chunk partials ----------------
__global__ __launch_bounds__(256) void kcombine(
    const float* __restrict__ ndp, const float* __restrict__ edp,
    const float* __restrict__ bbig, const int* __restrict__ opairs,
    float* __restrict__ out) {
  __shared__ float snd[184];
  __shared__ int spos[8];
  int b = blockIdx.x, tid = threadIdx.x;
  if (tid < 184) {
    int o = tid / 23, n = tid % 23;
    float s = 0.f;
#pragma unroll
    for (int c = 0; c < 4; ++c)
      s += ndp[((size_t)c*8192 + b*8 + o)*23 + n];
    snd[tid] = s;
  } else if (tid < 192) {
    int r = tid - 184;
    int oi = opairs[b*16 + r*2], oj = opairs[b*16 + r*2 + 1];
    int a = min(oi, oj), bb = max(oi, oj);
    spos[r] = 7*a - (a*(a+1))/2 + bb - 1;
  }
  __syncthreads();
  for (int g = tid; g < 644; g += 256) {
    int p = g / 23, n = g % 23;
    float ed = 0.f;
#pragma unroll
    for (int c = 0; c < 4; ++c)
      ed += edp[((size_t)c*28672 + b*28 + p)*23 + n];
    float val = 0.5f*(snd[d_pi[p]*23 + n] + snd[d_pj[p]*23 + n]) + ed + bbig[n];
    int slot = -1, below = 0;
#pragma unroll
    for (int r = 0; r < 8; ++r) {
      int pl = spos[r];
      slot = (pl == p) ? r : slot;
      below += (pl < p) ? 1 : 0;
    }
    if (n == 0) {
      out[OUT_IND + b*28 + p] = 1.f/(1.f + expf(-val));
      out[OUT_LAB + b*28 + p] = (slot >= 0) ? 1.f : 0.f;
    } else {
      int h = n - 1;
      if (slot >= 0) {
        int rr = b*8 + slot;
        if (h < 5)      out[OUT_LRP + rr*5  + h]     = val;
        else if (h < 8) out[OUT_CRP + rr*3  + (h-5)] = val;
        else            out[OUT_MRP + rr*14 + (h-8)] = val;
      } else {
        int s = p - below;
        int rr = b*20 + s;
        if (h < 5)      out[OUT_LRN + rr*5  + h]     = val;
        else if (h < 8) out[OUT_CRN + rr*3  + (h-5)] = val;
        else            out[OUT_MRN + rr*14 + (h-8)] = val;
      }
    }
  }
}

extern "C" void kernel_launch(void* const* d_in, const int* in_sizes, int n_in,
                              void* d_out, int out_size, void* d_ws, size_t ws_size,
                              hipStream_t stream) {
  const float* nf     = (const float*)d_in[0];
  const float* intf   = (const float*)d_in[1];
  const int*   opairs = (const int*)d_in[2];
  const float* w_ind1 = (const float*)d_in[3];
  const float* b_ind1 = (const float*)d_in[4];
  const float* w_ind2 = (const float*)d_in[5];
  const float* b_ind2 = (const float*)d_in[6];
  const float* w_rel  = (const float*)d_in[7];
  const float* b_rel  = (const float*)d_in[8];
  const float* w_cr   = (const float*)d_in[9];
  const float* b_cr   = (const float*)d_in[10];
  const float* w_lr   = (const float*)d_in[11];
  const float* b_lr   = (const float*)d_in[12];
  const float* w_mr   = (const float*)d_in[13];
  const float* b_mr   = (const float*)d_in[14];
  float* out = (float*)d_out;
  float* ws  = (float*)d_ws;

  float* wbig = ws + WS_WBIG;
  float* bmat = ws + WS_BMAT;
  float* bbig = ws + WS_BBIG;
  float* ndp  = ws + WS_ND;
  float* edp  = ws + WS_ED;

  prep1<<<177, 256, 0, stream>>>(w_rel, w_ind2, w_lr, w_cr, w_mr,
                                 b_ind1, b_ind2, b_rel, b_lr, b_cr, b_mr, bmat, bbig);
  prep2<<<1152, 256, 0, stream>>>(w_ind1, w_rel, bmat, wbig);
  kmain<<<576, 256, 0, stream>>>(nf, intf, wbig, ndp, edp);
  kcombine<<<1024, 256, 0, stream>>>(ndp, edp, bbig, opairs, out);
}